// Round 4
// baseline (506.431 us; speedup 1.0000x reference)
//
#include <hip/hip_runtime.h>

#define D 256  // class dimension, fixed by the problem

// One 64-lane wave processes one row per iteration:
//   lane l holds z[row, 4l..4l+3] and p[row, 4l..4l+3] as float4 (coalesced,
//   64 lanes x 16B = the whole 1 KiB row in one vector-memory instruction).
// Softmax dot-product in one pass:
//   res = sum(exp(x-m) * p) / sum(exp(x-m)),  term = 2 - 2*sqrt(res)
__global__ __launch_bounds__(256) void loss_kernel(const float* __restrict__ z,
                                                   const float* __restrict__ p,
                                                   float* __restrict__ out,
                                                   int n_rows) {
    const int lane          = threadIdx.x & 63;
    const int wave_in_block = threadIdx.x >> 6;
    const int waves_per_blk = blockDim.x >> 6;
    const int wave_id       = blockIdx.x * waves_per_blk + wave_in_block;
    const int total_waves   = gridDim.x * waves_per_blk;

    float acc = 0.0f;

    for (int row = wave_id; row < n_rows; row += total_waves) {
        const size_t base = (size_t)row * D + (size_t)lane * 4;
        const float4 x4 = *reinterpret_cast<const float4*>(z + base);
        const float4 p4 = *reinterpret_cast<const float4*>(p + base);

        // row max (numerical stability)
        float m = fmaxf(fmaxf(x4.x, x4.y), fmaxf(x4.z, x4.w));
        #pragma unroll
        for (int off = 32; off >= 1; off >>= 1)
            m = fmaxf(m, __shfl_xor(m, off, 64));

        const float e0 = __expf(x4.x - m);
        const float e1 = __expf(x4.y - m);
        const float e2 = __expf(x4.z - m);
        const float e3 = __expf(x4.w - m);

        float s = (e0 + e1) + (e2 + e3);                         // softmax denom
        float t = e0 * p4.x + e1 * p4.y + e2 * p4.z + e3 * p4.w; // numerator dot

        #pragma unroll
        for (int off = 32; off >= 1; off >>= 1) {
            s += __shfl_xor(s, off, 64);
            t += __shfl_xor(t, off, 64);
        }

        // (1 - res^0.5) / 0.5 == 2 - 2*sqrt(res)
        acc += 2.0f - 2.0f * sqrtf(t / s);
    }

    // acc is wave-uniform (s,t fully reduced); lane 0 of each wave deposits
    // its partial, thread 0 combines the block's 4 waves and does ONE atomic.
    __shared__ float sacc[4];
    if (lane == 0) sacc[wave_in_block] = acc;
    __syncthreads();
    if (threadIdx.x == 0) {
        float b = 0.0f;
        for (int w = 0; w < waves_per_blk; ++w) b += sacc[w];
        atomicAdd(out, b * (1.0f / (float)n_rows));
    }
}

extern "C" void kernel_launch(void* const* d_in, const int* in_sizes, int n_in,
                              void* d_out, int out_size, void* d_ws, size_t ws_size,
                              hipStream_t stream) {
    const float* z = (const float*)d_in[0];   // zp_pro_0, [N, 256] f32
    const float* p = (const float*)d_in[1];   // p0,       [N, 256] f32
    float* out = (float*)d_out;               // scalar f32

    const int n_rows = in_sizes[0] / D;       // 262144

    // d_out is poisoned to 0xAA before every timed launch — clear it.
    // hipMemsetAsync is graph-capture safe (becomes a memset node).
    hipMemsetAsync(out, 0, sizeof(float), stream);

    // 2048 blocks x 256 threads = 8192 waves; 32 rows per wave grid-stride.
    loss_kernel<<<dim3(2048), dim3(256), 0, stream>>>(z, p, out, n_rows);
}